// Round 7
// baseline (272.004 us; speedup 1.0000x reference)
//
#include <hip/hip_runtime.h>
#include <hip/hip_bf16.h>

#define IN_F   4096
#define OUT_F  11008
#define GS     128
#define M      32
#define NSPLIT 32        // one quant group per k-split (K=128 per block)
#define TILE_N 512       // 2 cols/thread at 256 threads
#define NT     22        // ceil(OUT_F/TILE_N), last tile clamped

typedef _Float16 half2_ __attribute__((ext_vector_type(2)));

__device__ __forceinline__ float bf16r(float v) {
    return __bfloat162float(__float2bfloat16(v));
}

// Kernel 0: pack x into f16 pairs over adjacent k-rows.
// xt2[kp*32 + m] = (f16(bf16r(x[m][2kp])), f16(bf16r(x[m][2kp+1])))
__global__ __launch_bounds__(256) void qk_prep(
    const float* __restrict__ x, unsigned int* __restrict__ xt2)
{
    int t  = blockIdx.x * 256 + threadIdx.x;   // 0 .. IN_F/2*M - 1
    int m  = t & (M - 1);
    int kp = t >> 5;
    float a = bf16r(x[m * IN_F + 2 * kp]);
    float b = bf16r(x[m * IN_F + 2 * kp + 1]);
    half2_ h = { (_Float16)a, (_Float16)b };
    xt2[t] = __builtin_bit_cast(unsigned int, h);
}

// Kernel 1: per-(group, n-tile) partial GEMM; partials bf16 in ws.
// 704 blocks x 4 waves = 11 waves/CU (best measured TLP shape).
// 2 cols/thread (int2 q-loads, 64 B/lane in flight via unroll 4);
// uniform x-reads amortized over both columns; fdot2 inner op.
__global__ __launch_bounds__(256) void qk_main(
    const unsigned int* __restrict__ xt2, const int* __restrict__ qw,
    const int* __restrict__ qz, const float* __restrict__ sc,
    __hip_bfloat16* __restrict__ part)
{
    const int g  = blockIdx.y;                 // quant group = k-split
    const int tx = threadIdx.x;                // 0..255

    int n0  = blockIdx.x * TILE_N + tx * 2;        // even
    int n0c = n0 > OUT_F - 2 ? OUT_F - 2 : n0;     // clamp for safe loads

    const float2 scv = *(const float2*)(sc + (size_t)g * OUT_F + n0c);
    const int2   qzv = *(const int2*)  (qz + (size_t)g * OUT_F + n0c);
    float s0 = bf16r(scv.x), s1 = bf16r(scv.y);
    float o0 = -(float)qzv.x * s0;      // w = q*s + (-z*s) == (q-z)*s exactly
    float o1 = -(float)qzv.y * s1;

    float acc0[M], acc1[M];
    #pragma unroll
    for (int m = 0; m < M; ++m) { acc0[m] = 0.f; acc1[m] = 0.f; }

    const int*          qp = qw  + (size_t)g * GS * OUT_F + n0c;
    const unsigned int* xr = xt2 + (size_t)g * (GS / 2) * M;   // uniform

    #pragma unroll 4
    for (int kp = 0; kp < GS / 2; ++kp) {      // 64 k-pairs
        int2 qa = *(const int2*)qp;            // k-row 2kp,  cols n0,n0+1
        int2 qb = *(const int2*)(qp + OUT_F);  // k-row 2kp+1
        qp += 2 * OUT_F;
        float w0a = (float)qa.x * s0 + o0, w0b = (float)qb.x * s0 + o0;
        float w1a = (float)qa.y * s1 + o1, w1b = (float)qb.y * s1 + o1;
        half2_ wh0 = { (_Float16)w0a, (_Float16)w0b };   // col n0, 2 k-rows
        half2_ wh1 = { (_Float16)w1a, (_Float16)w1b };   // col n0+1
        const uint4* xv = (const uint4*)(xr + kp * M);   // uniform addr
        #pragma unroll
        for (int mb = 0; mb < M / 4; ++mb) {
            uint4 u = xv[mb];
            half2_ x0 = __builtin_bit_cast(half2_, u.x);
            half2_ x1 = __builtin_bit_cast(half2_, u.y);
            half2_ x2 = __builtin_bit_cast(half2_, u.z);
            half2_ x3 = __builtin_bit_cast(half2_, u.w);
            acc0[4*mb+0] = __builtin_amdgcn_fdot2(x0, wh0, acc0[4*mb+0], false);
            acc1[4*mb+0] = __builtin_amdgcn_fdot2(x0, wh1, acc1[4*mb+0], false);
            acc0[4*mb+1] = __builtin_amdgcn_fdot2(x1, wh0, acc0[4*mb+1], false);
            acc1[4*mb+1] = __builtin_amdgcn_fdot2(x1, wh1, acc1[4*mb+1], false);
            acc0[4*mb+2] = __builtin_amdgcn_fdot2(x2, wh0, acc0[4*mb+2], false);
            acc1[4*mb+2] = __builtin_amdgcn_fdot2(x2, wh1, acc1[4*mb+2], false);
            acc0[4*mb+3] = __builtin_amdgcn_fdot2(x3, wh0, acc0[4*mb+3], false);
            acc1[4*mb+3] = __builtin_amdgcn_fdot2(x3, wh1, acc1[4*mb+3], false);
        }
    }

    if (n0 < OUT_F) {   // n0 even, OUT_F even -> n0+1 also valid
        __hip_bfloat16* pp = part + (size_t)g * M * OUT_F + n0;
        #pragma unroll
        for (int m = 0; m < M; ++m) {
            __hip_bfloat162 hv;
            hv.x = __float2bfloat16(acc0[m]);
            hv.y = __float2bfloat16(acc1[m]);
            *(__hip_bfloat162*)(pp + (size_t)m * OUT_F) = hv;
        }
    }
}

// Kernel 2: reduce NSPLIT bf16 partials + bias -> f32 out
__global__ __launch_bounds__(256) void qk_red(
    const __hip_bfloat16* __restrict__ part,
    const float* __restrict__ bias, float* __restrict__ out)
{
    const int m  = blockIdx.y;
    const int n0 = (blockIdx.x * 256 + threadIdx.x) * 2;
    if (n0 >= OUT_F) return;
    float a0 = 0.f, a1 = 0.f;
    #pragma unroll
    for (int s = 0; s < NSPLIT; ++s) {
        __hip_bfloat162 v = *(const __hip_bfloat162*)(
            part + ((size_t)s * M + m) * OUT_F + n0);
        a0 += __bfloat162float(v.x);
        a1 += __bfloat162float(v.y);
    }
    float2 r;
    r.x = a0 + bf16r(bias[n0]);
    r.y = a1 + bf16r(bias[n0 + 1]);
    *(float2*)(out + (size_t)m * OUT_F + n0) = r;
}

extern "C" void kernel_launch(void* const* d_in, const int* in_sizes, int n_in,
                              void* d_out, int out_size, void* d_ws, size_t ws_size,
                              hipStream_t stream) {
    const float* x    = (const float*)d_in[0];
    const int*   qw   = (const int*)  d_in[1];
    const int*   qz   = (const int*)  d_in[2];
    const float* sc   = (const float*)d_in[3];
    const float* bias = (const float*)d_in[4];
    float* out = (float*)d_out;

    unsigned int* xt2 = (unsigned int*)d_ws;                   // 256 KB
    __hip_bfloat16* part =
        (__hip_bfloat16*)((char*)d_ws + (size_t)(IN_F / 2) * M * 4);
    // part: NSPLIT*M*OUT_F bf16 = 22.5 MB

    qk_prep<<<(IN_F / 2) * M / 256, 256, 0, stream>>>(x, xt2);

    dim3 g1(NT, NSPLIT, 1);
    qk_main<<<g1, dim3(256, 1, 1), 0, stream>>>(xt2, qw, qz, sc, part);

    dim3 g2((OUT_F / 2 + 255) / 256, M, 1);
    qk_red<<<g2, dim3(256, 1, 1), 0, stream>>>(part, bias, out);
}

// Round 9
// 267.671 us; speedup vs baseline: 1.0162x; 1.0162x over previous
//
#include <hip/hip_runtime.h>
#include <hip/hip_bf16.h>

#define IN_F   4096
#define OUT_F  11008
#define GS     128
#define M      32
#define KCH    256       // k-rows per block = 2 quant groups
#define NSPLIT 16        // IN_F / KCH
#define TILE_N 256       // 1 col/thread at 256 threads
#define NT     43        // OUT_F / TILE_N == 43 exactly

typedef _Float16 half2_ __attribute__((ext_vector_type(2)));

__device__ __forceinline__ float bf16r(float v) {
    return __bfloat162float(__float2bfloat16(v));
}

// Kernel 0: pack x into f16 pairs over adjacent k-rows.
// xt2[kp*32 + m] = (f16(bf16r(x[m][2kp])), f16(bf16r(x[m][2kp+1])))
// bf16-rounded normals are exactly representable in f16; 256 KB, L2-resident.
__global__ __launch_bounds__(256) void qk_prep(
    const float* __restrict__ x, unsigned int* __restrict__ xt2)
{
    int t  = blockIdx.x * 256 + threadIdx.x;   // 0 .. IN_F/2*M - 1
    int m  = t & (M - 1);
    int kp = t >> 5;
    float a = bf16r(x[m * IN_F + 2 * kp]);
    float b = bf16r(x[m * IN_F + 2 * kp + 1]);
    half2_ h = { (_Float16)a, (_Float16)b };
    xt2[t] = __builtin_bit_cast(unsigned int, h);
}

// Kernel 1: per-(k-split, n-tile) partial GEMM; partials bf16 in ws.
// Best-measured config (round 6, 268.0 us): 256 threads / 4 waves,
// 688 blocks -> 10.75 waves/CU, 1 column/thread, 2 quant groups
// (256 k-rows) per block, fdot2 inner op, x via wave-uniform loads.
__global__ __launch_bounds__(256) void qk_main(
    const unsigned int* __restrict__ xt2, const int* __restrict__ qw,
    const int* __restrict__ qz, const float* __restrict__ sc,
    __hip_bfloat16* __restrict__ part)
{
    const int ks = blockIdx.y;                     // k-split (2 groups)
    const int tx = threadIdx.x;                    // 0..255
    const int n0 = blockIdx.x * TILE_N + tx;       // exact fit, no clamp

    float acc[M];
    #pragma unroll
    for (int m = 0; m < M; ++m) acc[m] = 0.f;

    #pragma unroll
    for (int sub = 0; sub < 2; ++sub) {            // 2 quant groups per block
        const int g = ks * 2 + sub;
        float s = bf16r(sc[(size_t)g * OUT_F + n0]);
        float o = -(float)qz[(size_t)g * OUT_F + n0] * s;  // w = q*s + o

        const int* qp = qw + (size_t)g * GS * OUT_F + n0;
        const unsigned int* xr = xt2 + (size_t)g * (GS / 2) * M;  // uniform

        #pragma unroll 4
        for (int kp = 0; kp < GS / 2; ++kp) {      // 64 k-pairs per group
            int q0 = qp[0];
            int q1 = qp[OUT_F];
            qp += 2 * OUT_F;
            float w0 = (float)q0 * s + o;          // == (q-z)*s exactly
            float w1 = (float)q1 * s + o;
            half2_ wh = { (_Float16)w0, (_Float16)w1 };
            const uint4* xv = (const uint4*)(xr + kp * M);  // uniform addr
            #pragma unroll
            for (int mb = 0; mb < M / 4; ++mb) {
                uint4 u = xv[mb];
                acc[4*mb+0] = __builtin_amdgcn_fdot2(
                    __builtin_bit_cast(half2_, u.x), wh, acc[4*mb+0], false);
                acc[4*mb+1] = __builtin_amdgcn_fdot2(
                    __builtin_bit_cast(half2_, u.y), wh, acc[4*mb+1], false);
                acc[4*mb+2] = __builtin_amdgcn_fdot2(
                    __builtin_bit_cast(half2_, u.z), wh, acc[4*mb+2], false);
                acc[4*mb+3] = __builtin_amdgcn_fdot2(
                    __builtin_bit_cast(half2_, u.w), wh, acc[4*mb+3], false);
            }
        }
    }

    __hip_bfloat16* pp = part + (size_t)ks * M * OUT_F + n0;
    #pragma unroll
    for (int m = 0; m < M; ++m)
        pp[(size_t)m * OUT_F] = __float2bfloat16(acc[m]);
}

// Kernel 2: reduce NSPLIT bf16 partials + bias -> f32 out
__global__ __launch_bounds__(256) void qk_red(
    const __hip_bfloat16* __restrict__ part,
    const float* __restrict__ bias, float* __restrict__ out)
{
    const int m  = blockIdx.y;
    const int n0 = (blockIdx.x * 256 + threadIdx.x) * 2;
    if (n0 >= OUT_F) return;
    float a0 = 0.f, a1 = 0.f;
    #pragma unroll
    for (int s = 0; s < NSPLIT; ++s) {
        __hip_bfloat162 v = *(const __hip_bfloat162*)(
            part + ((size_t)s * M + m) * OUT_F + n0);
        a0 += __bfloat162float(v.x);
        a1 += __bfloat162float(v.y);
    }
    float2 r;
    r.x = a0 + bf16r(bias[n0]);
    r.y = a1 + bf16r(bias[n0 + 1]);
    *(float2*)(out + (size_t)m * OUT_F + n0) = r;
}

extern "C" void kernel_launch(void* const* d_in, const int* in_sizes, int n_in,
                              void* d_out, int out_size, void* d_ws, size_t ws_size,
                              hipStream_t stream) {
    const float* x    = (const float*)d_in[0];
    const int*   qw   = (const int*)  d_in[1];
    const int*   qz   = (const int*)  d_in[2];
    const float* sc   = (const float*)d_in[3];
    const float* bias = (const float*)d_in[4];
    float* out = (float*)d_out;

    unsigned int* xt2 = (unsigned int*)d_ws;                   // 256 KB
    __hip_bfloat16* part =
        (__hip_bfloat16*)((char*)d_ws + (size_t)(IN_F / 2) * M * 4);
    // part: NSPLIT*M*OUT_F bf16 = 11.3 MB

    qk_prep<<<(IN_F / 2) * M / 256, 256, 0, stream>>>(x, xt2);

    dim3 g1(NT, NSPLIT, 1);
    qk_main<<<g1, dim3(256, 1, 1), 0, stream>>>(xt2, qw, qz, sc, part);

    dim3 g2((OUT_F / 2 + 255) / 256, M, 1);
    qk_red<<<g2, dim3(256, 1, 1), 0, stream>>>(part, bias, out);
}